// Round 1
// baseline (702.696 us; speedup 1.0000x reference)
//
#include <hip/hip_runtime.h>
#include <hip/hip_bf16.h>

#define NNODES 50000
#define NREL   8
#define HID    64
#define NCLS   16
#define NEDGE  1600000
#define NTGT   8192

__device__ __forceinline__ float elu1(float x) { return x > 0.f ? x : expm1f(x); }

// select inv[r] with r in a VGPR via cndmask tree (all indices constant)
__device__ __forceinline__ float sel8(const float inv[8], int r) {
  float lo = (r & 2) ? ((r & 1) ? inv[3] : inv[2]) : ((r & 1) ? inv[1] : inv[0]);
  float hi = (r & 2) ? ((r & 1) ? inv[7] : inv[6]) : ((r & 1) ? inv[5] : inv[4]);
  return (r & 4) ? hi : lo;
}

// --- K1: per-(dst, rel) edge counts -----------------------------------------
__global__ void count_kernel(const int* __restrict__ ei, const int* __restrict__ et,
                             int* __restrict__ cnt) {
  int e = blockIdx.x * blockDim.x + threadIdx.x;
  if (e >= NEDGE) return;
  int dst = ei[NEDGE + e];
  int rel = et[e];
  atomicAdd(&cnt[dst * NREL + rel], 1);
}

// --- K2: single-block exclusive scan of per-node degrees -> CSR row_ptr ------
__global__ void scan_kernel(const int* __restrict__ cnt, int* __restrict__ row_ptr,
                            int* __restrict__ row_fill) {
  const int TT = 1024;
  const int CH = (NNODES + TT - 1) / TT;  // 49 nodes per thread
  int tid = threadIdx.x;
  int lane = tid & 63, wid = tid >> 6;
  int start = tid * CH;
  int stop = min(start + CH, NNODES);

  int s = 0;
  for (int n = start; n < stop; ++n) {
    int d = 0;
#pragma unroll
    for (int r = 0; r < NREL; ++r) d += cnt[n * NREL + r];
    s += d;
  }
  // wave-level inclusive scan
  int v = s;
#pragma unroll
  for (int off = 1; off < 64; off <<= 1) {
    int u = __shfl_up(v, off);
    if (lane >= off) v += u;
  }
  __shared__ int wsum[16];
  if (lane == 63) wsum[wid] = v;
  __syncthreads();
  if (tid == 0) {
    int run = 0;
#pragma unroll
    for (int i = 0; i < 16; ++i) { int t = wsum[i]; wsum[i] = run; run += t; }
  }
  __syncthreads();
  int run = (v - s) + wsum[wid];  // exclusive prefix for this thread
  for (int n = start; n < stop; ++n) {
    row_ptr[n]  = run;
    row_fill[n] = run;
    int d = 0;
#pragma unroll
    for (int r = 0; r < NREL; ++r) d += cnt[n * NREL + r];
    run += d;
  }
  if (tid == TT - 1) row_ptr[NNODES] = run;  // == NEDGE
}

// --- K3: scatter edges into CSR slots (src|rel packed; src<65536, rel<8) -----
__global__ void scatter_kernel(const int* __restrict__ ei, const int* __restrict__ et,
                               int* __restrict__ row_fill, int* __restrict__ ep) {
  int e = blockIdx.x * blockDim.x + threadIdx.x;
  if (e >= NEDGE) return;
  int src = ei[e];
  int dst = ei[NEDGE + e];
  int rel = et[e];
  int pos = atomicAdd(&row_fill[dst], 1);
  ep[pos] = src | (rel << 16);
}

// --- K4: conv1 — one wave per node, lane = hidden channel --------------------
__global__ void conv1_kernel(const int* __restrict__ row_ptr, const int* __restrict__ ep,
                             const int* __restrict__ cnt,
                             const float* __restrict__ w1, const float* __restrict__ root1,
                             const float* __restrict__ bias1, float* __restrict__ h1) {
  int wave = blockIdx.x * (blockDim.x >> 6) + (threadIdx.x >> 6);
  if (wave >= NNODES) return;
  int lane = threadIdx.x & 63;
  int n = wave;
  float inv[8];
#pragma unroll
  for (int r = 0; r < NREL; ++r) inv[r] = 1.0f / (float)max(cnt[n * NREL + r], 1);
  int beg = row_ptr[n], end = row_ptr[n + 1];
  float acc = 0.f;
  int e = beg;
  for (; e + 4 <= end; e += 4) {  // unroll-4: 4 gathers in flight
    int p0 = ep[e], p1 = ep[e + 1], p2 = ep[e + 2], p3 = ep[e + 3];
    float a0 = w1[((p0 >> 16) * NNODES + (p0 & 0xFFFF)) * HID + lane];
    float a1 = w1[((p1 >> 16) * NNODES + (p1 & 0xFFFF)) * HID + lane];
    float a2 = w1[((p2 >> 16) * NNODES + (p2 & 0xFFFF)) * HID + lane];
    float a3 = w1[((p3 >> 16) * NNODES + (p3 & 0xFFFF)) * HID + lane];
    acc = fmaf(a0, sel8(inv, p0 >> 16), acc);
    acc = fmaf(a1, sel8(inv, p1 >> 16), acc);
    acc = fmaf(a2, sel8(inv, p2 >> 16), acc);
    acc = fmaf(a3, sel8(inv, p3 >> 16), acc);
  }
  for (; e < end; ++e) {
    int p = ep[e];
    float a = w1[((p >> 16) * NNODES + (p & 0xFFFF)) * HID + lane];
    acc = fmaf(a, sel8(inv, p >> 16), acc);
  }
  float v = acc + root1[n * HID + lane] + bias1[lane];
  h1[n * HID + lane] = elu1(v);
}

// --- K5: conv2 — only dst < NTGT matter; aggregate per relation, then
//         transform once per node: h2 = ELU(sum_r inv_r*(S_r @ W2_r) + h1@root2 + b2)
__global__ void conv2_kernel(const int* __restrict__ row_ptr, const int* __restrict__ ep,
                             const int* __restrict__ cnt, const float* __restrict__ h1,
                             const float* __restrict__ w2, const float* __restrict__ root2,
                             const float* __restrict__ bias2, float* __restrict__ h2) {
  int wave = blockIdx.x * (blockDim.x >> 6) + (threadIdx.x >> 6);
  if (wave >= NTGT) return;
  int lane = threadIdx.x & 63;
  int n = wave;
  float inv[8];
#pragma unroll
  for (int r = 0; r < NREL; ++r) inv[r] = 1.0f / (float)max(cnt[n * NREL + r], 1);
  int beg = row_ptr[n], end = row_ptr[n + 1];
  float acc[8] = {0.f, 0.f, 0.f, 0.f, 0.f, 0.f, 0.f, 0.f};
  int e = beg;
  for (; e + 2 <= end; e += 2) {
    int p0 = ep[e], p1 = ep[e + 1];
    float hv0 = h1[(p0 & 0xFFFF) * HID + lane];
    float hv1 = h1[(p1 & 0xFFFF) * HID + lane];
    int r0 = p0 >> 16, r1 = p1 >> 16;
#pragma unroll
    for (int r = 0; r < NREL; ++r) {
      acc[r] += (r0 == r) ? hv0 : 0.f;
      acc[r] += (r1 == r) ? hv1 : 0.f;
    }
  }
  for (; e < end; ++e) {
    int p = ep[e];
    float hv = h1[(p & 0xFFFF) * HID + lane];
    int r0 = p >> 16;
#pragma unroll
    for (int r = 0; r < NREL; ++r) acc[r] += (r0 == r) ? hv : 0.f;
  }
#pragma unroll
  for (int r = 0; r < NREL; ++r) acc[r] *= inv[r];

  float h1v = h1[n * HID + lane];
  float o = bias2[lane];
#pragma unroll
  for (int r = 0; r < NREL; ++r) {
    float a = acc[r];
#pragma unroll 16
    for (int k = 0; k < HID; ++k)
      o = fmaf(__shfl(a, k), w2[(r * HID + k) * HID + lane], o);
  }
#pragma unroll 16
  for (int k = 0; k < HID; ++k)
    o = fmaf(__shfl(h1v, k), root2[k * HID + lane], o);
  h2[n * HID + lane] = elu1(o);
}

// --- K6: linear head on the target slice -------------------------------------
__global__ void head_kernel(const float* __restrict__ h2, const float* __restrict__ lin_w,
                            const float* __restrict__ lin_b, float* __restrict__ out) {
  int t = blockIdx.x * blockDim.x + threadIdx.x;
  if (t >= NTGT * NCLS) return;
  int n = t >> 4, c = t & 15;
  float acc = lin_b[c];
#pragma unroll 16
  for (int k = 0; k < HID; ++k)
    acc = fmaf(h2[n * HID + k], lin_w[k * NCLS + c], acc);
  out[t] = acc;
}

extern "C" void kernel_launch(void* const* d_in, const int* in_sizes, int n_in,
                              void* d_out, int out_size, void* d_ws, size_t ws_size,
                              hipStream_t stream) {
  const int*   ei    = (const int*)d_in[0];
  const int*   et    = (const int*)d_in[1];
  const float* w1    = (const float*)d_in[3];
  const float* root1 = (const float*)d_in[4];
  const float* bias1 = (const float*)d_in[5];
  const float* w2    = (const float*)d_in[6];
  const float* root2 = (const float*)d_in[7];
  const float* bias2 = (const float*)d_in[8];
  const float* lin_w = (const float*)d_in[9];
  const float* lin_b = (const float*)d_in[10];
  float* out = (float*)d_out;

  // workspace carve-up (~23.3 MB total)
  char* ws = (char*)d_ws;
  size_t off = 0;
  auto alloc = [&](size_t bytes) {
    void* p = ws + off;
    off = (off + bytes + 255) & ~(size_t)255;
    return p;
  };
  int*   cnt      = (int*)alloc((size_t)NNODES * NREL * 4);
  int*   row_ptr  = (int*)alloc((size_t)(NNODES + 1) * 4);
  int*   row_fill = (int*)alloc((size_t)NNODES * 4);
  int*   ep       = (int*)alloc((size_t)NEDGE * 4);
  float* h1       = (float*)alloc((size_t)NNODES * HID * 4);
  float* h2       = (float*)alloc((size_t)NTGT * HID * 4);

  hipMemsetAsync(cnt, 0, (size_t)NNODES * NREL * sizeof(int), stream);
  count_kernel<<<(NEDGE + 255) / 256, 256, 0, stream>>>(ei, et, cnt);
  scan_kernel<<<1, 1024, 0, stream>>>(cnt, row_ptr, row_fill);
  scatter_kernel<<<(NEDGE + 255) / 256, 256, 0, stream>>>(ei, et, row_fill, ep);
  conv1_kernel<<<(NNODES * HID + 255) / 256, 256, 0, stream>>>(row_ptr, ep, cnt, w1, root1, bias1, h1);
  conv2_kernel<<<(NTGT * HID + 255) / 256, 256, 0, stream>>>(row_ptr, ep, cnt, h1, w2, root2, bias2, h2);
  head_kernel<<<(NTGT * NCLS + 255) / 256, 256, 0, stream>>>(h2, lin_w, lin_b, out);
}